// Round 2
// baseline (9306.848 us; speedup 1.0000x reference)
//
#include <hip/hip_runtime.h>
#include <hip/hip_bf16.h>

#define NN 100000
#define EE 1600000
#define CC 128

// ---------------- degree: deg[d] += 1 per edge ----------------
__global__ __launch_bounds__(256) void k_deg(const int* __restrict__ dst,
                                             float* __restrict__ deg) {
  int e = blockIdx.x * 256 + threadIdx.x;
  if (e < EE) atomicAdd(&deg[dst[e]], 1.0f);
}

// ---------------- layer-1 scatter (Cin=3) ----------------
__global__ __launch_bounds__(256) void k_scatter3(const int* __restrict__ src,
                                                  const int* __restrict__ dst,
                                                  const float* __restrict__ pos,
                                                  float* __restrict__ msg) {
  int e = blockIdx.x * 256 + threadIdx.x;
  if (e < EE) {
    int s = src[e], d = dst[e];
    atomicAdd(&msg[d * 3 + 0], pos[s * 3 + 0]);
    atomicAdd(&msg[d * 3 + 1], pos[s * 3 + 1]);
    atomicAdd(&msg[d * 3 + 2], pos[s * 3 + 2]);
  }
}

// ---------------- layer-1 node update (Cin=3 -> 128) ----------------
__global__ __launch_bounds__(128) void k_node1(
    const float* __restrict__ msg, const float* __restrict__ deg,
    const float* __restrict__ pos, const float* __restrict__ wl,
    const float* __restrict__ bl, const float* __restrict__ wr,
    const float* __restrict__ g, const float* __restrict__ be,
    const float* __restrict__ m, const float* __restrict__ v,
    float* __restrict__ y) {
  int n = blockIdx.x;
  int c = threadIdx.x;
  __shared__ float sa[3], sp[3];
  if (c < 3) {
    float dg = fmaxf(deg[n], 1.0f);
    sa[c] = msg[n * 3 + c] / dg;
    sp[c] = pos[n * 3 + c];
  }
  __syncthreads();
  float acc = bl[c];
#pragma unroll
  for (int k = 0; k < 3; k++) {
    acc += sa[k] * wl[k * CC + c];
    acc += sp[k] * wr[k * CC + c];
  }
  float sc = g[c] * rsqrtf(v[c] + 1e-5f);
  float yv = (acc - m[c]) * sc + be[c];
  y[(long long)n * CC + c] = fmaxf(yv, 0.0f);
}

// ---------------- scatter for Cin=128: 32 threads per edge ----------------
__global__ __launch_bounds__(256) void k_scatter128(const int* __restrict__ src,
                                                    const int* __restrict__ dst,
                                                    const float* __restrict__ x,
                                                    float* __restrict__ msg) {
  long long t = (long long)blockIdx.x * 256 + threadIdx.x;
  int e = (int)(t >> 5);
  if (e >= EE) return;
  int ch = ((int)t & 31) * 4;
  int s = src[e], d = dst[e];
  const float4 val = *(const float4*)(x + (long long)s * CC + ch);
  float* mp = msg + (long long)d * CC + ch;
  atomicAdd(mp + 0, val.x);
  atomicAdd(mp + 1, val.y);
  atomicAdd(mp + 2, val.z);
  atomicAdd(mp + 3, val.w);
}

// ---------------- SAGE node update (Cin=128): 8 nodes/block, IN-PLACE safe ----
__global__ __launch_bounds__(128) void k_sage(
    const float* __restrict__ msg, const float* __restrict__ deg,
    const float* __restrict__ wl, const float* __restrict__ bl,
    const float* __restrict__ wr, const float* __restrict__ g,
    const float* __restrict__ be, const float* __restrict__ m,
    const float* __restrict__ v, float* __restrict__ x /* in-out */) {
  int n0 = blockIdx.x * 8;
  int c = threadIdx.x;
  __shared__ float sx[8][CC];
  __shared__ float sa[8][CC];
#pragma unroll
  for (int j = 0; j < 8; j++) {
    int n = n0 + j;
    float rd = 1.0f / fmaxf(deg[n], 1.0f);
    sx[j][c] = x[(long long)n * CC + c];
    sa[j][c] = msg[(long long)n * CC + c] * rd;
  }
  __syncthreads();
  float accL[8];
  float accR[8];
#pragma unroll
  for (int j = 0; j < 8; j++) { accL[j] = 0.0f; accR[j] = 0.0f; }
#pragma unroll 4
  for (int k = 0; k < CC; k++) {
    float wlk = wl[k * CC + c];
    float wrk = wr[k * CC + c];
#pragma unroll
    for (int j = 0; j < 8; j++) {
      accL[j] += sa[j][k] * wlk;
      accR[j] += sx[j][k] * wrk;
    }
  }
  float blc = bl[c];
  float sc = g[c] * rsqrtf(v[c] + 1e-5f);
  float mm = m[c];
  float bb = be[c];
#pragma unroll
  for (int j = 0; j < 8; j++) {
    float acc = accL[j] + accR[j] + blc;
    float yv = (acc - mm) * sc + bb;
    x[(long long)(n0 + j) * CC + c] = fmaxf(yv, 0.0f);
  }
}

// ---------------- dense: y = act(x @ w + b), 8 nodes/block, in-place safe ----
template <bool RELU>
__global__ __launch_bounds__(128) void k_dense(const float* __restrict__ x,
                                               const float* __restrict__ w,
                                               const float* __restrict__ b,
                                               float* __restrict__ y) {
  int n0 = blockIdx.x * 8;
  int c = threadIdx.x;
  __shared__ float sx[8][CC];
#pragma unroll
  for (int j = 0; j < 8; j++) sx[j][c] = x[(long long)(n0 + j) * CC + c];
  __syncthreads();
  float acc[8];
#pragma unroll
  for (int j = 0; j < 8; j++) acc[j] = 0.0f;
#pragma unroll 4
  for (int k = 0; k < CC; k++) {
    float wk = w[k * CC + c];
#pragma unroll
    for (int j = 0; j < 8; j++) acc[j] += sx[j][k] * wk;
  }
  float bc = b[c];
#pragma unroll
  for (int j = 0; j < 8; j++) {
    float vv = acc[j] + bc;
    if (RELU) vv = fmaxf(vv, 0.0f);
    y[(long long)(n0 + j) * CC + c] = vv;
  }
}

extern "C" void kernel_launch(void* const* d_in, const int* in_sizes, int n_in,
                              void* d_out, int out_size, void* d_ws,
                              size_t ws_size, hipStream_t stream) {
  const float* pos = (const float*)d_in[0];
  const int* ei = (const int*)d_in[1];
  const int* src = ei;
  const int* dst = ei + EE;
  auto P = [&](int i) { return (const float*)d_in[i]; };

  // workspace layout (floats): deg | x | msg  => (2*N*C + N)*4 B ~ 102.8 MB
  float* deg = (float*)d_ws;
  float* x = deg + NN;
  float* msg = x + (size_t)NN * CC;

  hipMemsetAsync(deg, 0, NN * sizeof(float), stream);
  hipMemsetAsync(msg, 0, (size_t)NN * 3 * sizeof(float), stream);

  k_deg<<<(EE + 255) / 256, 256, 0, stream>>>(dst, deg);
  k_scatter3<<<(EE + 255) / 256, 256, 0, stream>>>(src, dst, pos, msg);
  k_node1<<<NN, 128, 0, stream>>>(msg, deg, pos, P(2), P(3), P(4), P(5), P(6),
                                  P(7), P(8), x);

  for (int l = 1; l < 4; l++) {
    int base = 2 + 7 * l;
    hipMemsetAsync(msg, 0, (size_t)NN * CC * sizeof(float), stream);
    k_scatter128<<<EE / 8, 256, 0, stream>>>(src, dst, x, msg);
    k_sage<<<NN / 8, 128, 0, stream>>>(msg, deg, P(base), P(base + 1),
                                       P(base + 2), P(base + 3), P(base + 4),
                                       P(base + 5), P(base + 6), x);
  }

  // FC head: x = relu(x@wf1+bf1); x = x@wf2+bf2; out = x@wf3+bf3
  k_dense<true><<<NN / 8, 128, 0, stream>>>(x, P(30), P(31), x);
  k_dense<false><<<NN / 8, 128, 0, stream>>>(x, P(32), P(33), x);
  k_dense<false><<<NN / 8, 128, 0, stream>>>(x, P(34), P(35), (float*)d_out);
}

// Round 3
// 1730.928 us; speedup vs baseline: 5.3768x; 5.3768x over previous
//
#include <hip/hip_runtime.h>
#include <hip/hip_bf16.h>

#define NN 100000
#define EE 1600000
#define CC 128

// ---------------- in-degree count (int atomics) ----------------
__global__ __launch_bounds__(256) void k_count(const int* __restrict__ dst,
                                               int* __restrict__ degi) {
  int e = blockIdx.x * 256 + threadIdx.x;
  if (e < EE) atomicAdd(&degi[dst[e]], 1);
}

// ---------------- exclusive prefix sum over degi -> off[NN+1] ----------------
__global__ __launch_bounds__(1024) void k_scan(const int* __restrict__ degi,
                                               int* __restrict__ off) {
  __shared__ int part[1024];
  const int CH = (NN + 1023) / 1024;  // 98
  int t = threadIdx.x;
  int lo = t * CH;
  int hi = lo + CH; if (hi > NN) hi = NN; if (lo > NN) lo = NN;
  int s = 0;
  for (int i = lo; i < hi; i++) s += degi[i];
  part[t] = s;
  __syncthreads();
  for (int d = 1; d < 1024; d <<= 1) {
    int v = (t >= d) ? part[t - d] : 0;
    __syncthreads();
    part[t] += v;
    __syncthreads();
  }
  int run = part[t] - s;  // exclusive prefix of this chunk
  for (int i = lo; i < hi; i++) { off[i] = run; run += degi[i]; }
  if (t == 1023) off[NN] = run;  // == EE
}

// ---------------- fill CSR: csr[off[d] + cursor[d]++] = src ----------------
__global__ __launch_bounds__(256) void k_fill(const int* __restrict__ src,
                                              const int* __restrict__ dst,
                                              const int* __restrict__ off,
                                              int* __restrict__ cursor,
                                              int* __restrict__ csr) {
  int e = blockIdx.x * 256 + threadIdx.x;
  if (e < EE) {
    int d = dst[e];
    int p = atomicAdd(&cursor[d], 1);
    csr[off[d] + p] = src[e];
  }
}

// ---------------- layer-1 aggregate (Cin=3): mean of pos over neighbors ------
__global__ __launch_bounds__(256) void k_agg3(const int* __restrict__ off,
                                              const int* __restrict__ csr,
                                              const float* __restrict__ pos,
                                              float* __restrict__ agg3) {
  int n = blockIdx.x * 256 + threadIdx.x;
  if (n >= NN) return;
  int b = off[n], e = off[n + 1];
  float a0 = 0.f, a1 = 0.f, a2 = 0.f;
  for (int i = b; i < e; i++) {
    int s = csr[i];
    a0 += pos[s * 3 + 0];
    a1 += pos[s * 3 + 1];
    a2 += pos[s * 3 + 2];
  }
  float rd = 1.0f / fmaxf((float)(e - b), 1.0f);
  agg3[n * 3 + 0] = a0 * rd;
  agg3[n * 3 + 1] = a1 * rd;
  agg3[n * 3 + 2] = a2 * rd;
}

// ---------------- layer-1 node update (Cin=3 -> 128) ----------------
__global__ __launch_bounds__(128) void k_node1(
    const float* __restrict__ agg3, const float* __restrict__ pos,
    const float* __restrict__ wl, const float* __restrict__ bl,
    const float* __restrict__ wr, const float* __restrict__ g,
    const float* __restrict__ be, const float* __restrict__ m,
    const float* __restrict__ v, float* __restrict__ y) {
  int n = blockIdx.x;
  int c = threadIdx.x;
  __shared__ float sa[3], sp[3];
  if (c < 3) {
    sa[c] = agg3[n * 3 + c];
    sp[c] = pos[n * 3 + c];
  }
  __syncthreads();
  float acc = bl[c];
#pragma unroll
  for (int k = 0; k < 3; k++) {
    acc += sa[k] * wl[k * CC + c];
    acc += sp[k] * wr[k * CC + c];
  }
  float sc = g[c] * rsqrtf(v[c] + 1e-5f);
  float yv = (acc - m[c]) * sc + be[c];
  y[(long long)n * CC + c] = fmaxf(yv, 0.0f);
}

// ---------------- aggregate (C=128): 32 threads/node, gather rows ----------
__global__ __launch_bounds__(256) void k_aggregate(const int* __restrict__ off,
                                                   const int* __restrict__ csr,
                                                   const float* __restrict__ x,
                                                   float* __restrict__ agg) {
  int n = blockIdx.x * 8 + (threadIdx.x >> 5);
  int lane = threadIdx.x & 31;  // float4 slot: 32*4 = 128 channels
  int b = off[n], e = off[n + 1];
  float4 acc = make_float4(0.f, 0.f, 0.f, 0.f);
  for (int i = b; i < e; i++) {
    int s = csr[i];
    float4 v = ((const float4*)(x + (long long)s * CC))[lane];
    acc.x += v.x; acc.y += v.y; acc.z += v.z; acc.w += v.w;
  }
  float rd = 1.0f / fmaxf((float)(e - b), 1.0f);
  acc.x *= rd; acc.y *= rd; acc.z *= rd; acc.w *= rd;
  ((float4*)(agg + (long long)n * CC))[lane] = acc;
}

// ---------------- SAGE node update (Cin=128): 8 nodes/block, IN-PLACE ------
__global__ __launch_bounds__(128) void k_sage(
    const float* __restrict__ agg, const float* __restrict__ wl,
    const float* __restrict__ bl, const float* __restrict__ wr,
    const float* __restrict__ g, const float* __restrict__ be,
    const float* __restrict__ m, const float* __restrict__ v,
    float* __restrict__ x /* in-out */) {
  int n0 = blockIdx.x * 8;
  int c = threadIdx.x;
  __shared__ float sx[8][CC];
  __shared__ float sa[8][CC];
#pragma unroll
  for (int j = 0; j < 8; j++) {
    int n = n0 + j;
    sx[j][c] = x[(long long)n * CC + c];
    sa[j][c] = agg[(long long)n * CC + c];
  }
  __syncthreads();
  float accL[8];
  float accR[8];
#pragma unroll
  for (int j = 0; j < 8; j++) { accL[j] = 0.0f; accR[j] = 0.0f; }
#pragma unroll 4
  for (int k = 0; k < CC; k++) {
    float wlk = wl[k * CC + c];
    float wrk = wr[k * CC + c];
#pragma unroll
    for (int j = 0; j < 8; j++) {
      accL[j] += sa[j][k] * wlk;
      accR[j] += sx[j][k] * wrk;
    }
  }
  float blc = bl[c];
  float sc = g[c] * rsqrtf(v[c] + 1e-5f);
  float mm = m[c];
  float bb = be[c];
#pragma unroll
  for (int j = 0; j < 8; j++) {
    float acc = accL[j] + accR[j] + blc;
    float yv = (acc - mm) * sc + bb;
    x[(long long)(n0 + j) * CC + c] = fmaxf(yv, 0.0f);
  }
}

// ---------------- dense: y = act(x @ w + b), 8 nodes/block ----------------
template <bool RELU>
__global__ __launch_bounds__(128) void k_dense(const float* __restrict__ x,
                                               const float* __restrict__ w,
                                               const float* __restrict__ b,
                                               float* __restrict__ y) {
  int n0 = blockIdx.x * 8;
  int c = threadIdx.x;
  __shared__ float sx[8][CC];
#pragma unroll
  for (int j = 0; j < 8; j++) sx[j][c] = x[(long long)(n0 + j) * CC + c];
  __syncthreads();
  float acc[8];
#pragma unroll
  for (int j = 0; j < 8; j++) acc[j] = 0.0f;
#pragma unroll 4
  for (int k = 0; k < CC; k++) {
    float wk = w[k * CC + c];
#pragma unroll
    for (int j = 0; j < 8; j++) acc[j] += sx[j][k] * wk;
  }
  float bc = b[c];
#pragma unroll
  for (int j = 0; j < 8; j++) {
    float vv = acc[j] + bc;
    if (RELU) vv = fmaxf(vv, 0.0f);
    y[(long long)(n0 + j) * CC + c] = vv;
  }
}

extern "C" void kernel_launch(void* const* d_in, const int* in_sizes, int n_in,
                              void* d_out, int out_size, void* d_ws,
                              size_t ws_size, hipStream_t stream) {
  const float* pos = (const float*)d_in[0];
  const int* ei = (const int*)d_in[1];
  const int* src = ei;
  const int* dst = ei + EE;
  auto P = [&](int i) { return (const float*)d_in[i]; };

  // workspace (ints then floats): degi[N] | cursor[N] | off[N+8] | csr[E] | x[N*C]
  // total ~58.8 MB
  int* degi = (int*)d_ws;
  int* cursor = degi + NN;
  int* off = cursor + NN;
  int* csr = off + NN + 8;
  float* x = (float*)(csr + EE);
  float* agg = (float*)d_out;  // scratch until the final dense write

  hipMemsetAsync(degi, 0, NN * sizeof(int), stream);
  hipMemsetAsync(cursor, 0, NN * sizeof(int), stream);

  k_count<<<(EE + 255) / 256, 256, 0, stream>>>(dst, degi);
  k_scan<<<1, 1024, 0, stream>>>(degi, off);
  k_fill<<<(EE + 255) / 256, 256, 0, stream>>>(src, dst, off, cursor, csr);

  // layer 1 (Cin=3)
  k_agg3<<<(NN + 255) / 256, 256, 0, stream>>>(off, csr, pos, agg);
  k_node1<<<NN, 128, 0, stream>>>(agg, pos, P(2), P(3), P(4), P(5), P(6), P(7),
                                  P(8), x);

  // layers 2..4 (Cin=128)
  for (int l = 1; l < 4; l++) {
    int base = 2 + 7 * l;
    k_aggregate<<<NN / 8, 256, 0, stream>>>(off, csr, x, agg);
    k_sage<<<NN / 8, 128, 0, stream>>>(agg, P(base), P(base + 1), P(base + 2),
                                       P(base + 3), P(base + 4), P(base + 5),
                                       P(base + 6), x);
  }

  // FC head: x = relu(x@wf1+bf1); x = x@wf2+bf2; out = x@wf3+bf3
  k_dense<true><<<NN / 8, 128, 0, stream>>>(x, P(30), P(31), x);
  k_dense<false><<<NN / 8, 128, 0, stream>>>(x, P(32), P(33), x);
  k_dense<false><<<NN / 8, 128, 0, stream>>>(x, P(34), P(35), (float*)d_out);
}

// Round 4
// 1620.788 us; speedup vs baseline: 5.7422x; 1.0680x over previous
//
#include <hip/hip_runtime.h>

#define NN 100000
#define EE 1600000
#define CC 128
#define NP 100032  // padded to 64-row tiles (1563 * 64)

typedef unsigned short u16;
typedef __attribute__((ext_vector_type(8))) short bf16x8;
typedef __attribute__((ext_vector_type(4))) float f32x4;

#define MFMA(a, b, c) __builtin_amdgcn_mfma_f32_16x16x32_bf16(a, b, c, 0, 0, 0)

__device__ __forceinline__ void split2(float x, u16& h, u16& l) {
  unsigned b = __float_as_uint(x);
  h = (u16)(b >> 16);
  float hf = __uint_as_float(b & 0xffff0000u);
  l = (u16)(__float_as_uint(x - hf) >> 16);
}

// ---------------- CSR build ----------------
__global__ __launch_bounds__(256) void k_count(const int* __restrict__ dst,
                                               int* __restrict__ degi) {
  int e = blockIdx.x * 256 + threadIdx.x;
  if (e < EE) atomicAdd(&degi[dst[e]], 1);
}

__global__ __launch_bounds__(1024) void k_scan(const int* __restrict__ degi,
                                               int* __restrict__ off) {
  __shared__ int part[1024];
  const int CH = (NN + 1023) / 1024;
  int t = threadIdx.x;
  int lo = t * CH;
  int hi = lo + CH; if (hi > NN) hi = NN; if (lo > NN) lo = NN;
  int s = 0;
  for (int i = lo; i < hi; i++) s += degi[i];
  part[t] = s;
  __syncthreads();
  for (int d = 1; d < 1024; d <<= 1) {
    int v = (t >= d) ? part[t - d] : 0;
    __syncthreads();
    part[t] += v;
    __syncthreads();
  }
  int run = part[t] - s;
  for (int i = lo; i < hi; i++) { off[i] = run; run += degi[i]; }
  if (t == 1023) off[NN] = run;
}

__global__ __launch_bounds__(256) void k_fill(const int* __restrict__ src,
                                              const int* __restrict__ dst,
                                              const int* __restrict__ off,
                                              int* __restrict__ cursor,
                                              int* __restrict__ csr) {
  int e = blockIdx.x * 256 + threadIdx.x;
  if (e < EE) {
    int d = dst[e];
    int p = atomicAdd(&cursor[d], 1);
    csr[off[d] + p] = src[e];
  }
}

// ---------------- weight pack: fp32 [k][n] -> split bf16 transposed [n][k] ----
struct WPtrs { const float* w[9]; };
__global__ __launch_bounds__(256) void k_packw(WPtrs wp, u16* __restrict__ outh,
                                               u16* __restrict__ outl) {
  int t = blockIdx.x * 256 + threadIdx.x;  // 9 * 16384
  int mat = t >> 14;
  int ij = t & 16383;          // ij = k*128 + n
  int k = ij >> 7, n = ij & 127;
  float val = wp.w[mat][ij];
  u16 h, l;
  split2(val, h, l);
  size_t d = (size_t)mat * 16384 + n * CC + k;
  outh[d] = h;
  outl[d] = l;
}

// ---------------- layer-1 aggregate (Cin=3) ----------------
__global__ __launch_bounds__(256) void k_agg3(const int* __restrict__ off,
                                              const int* __restrict__ csr,
                                              const float* __restrict__ pos,
                                              float* __restrict__ agg3) {
  int n = blockIdx.x * 256 + threadIdx.x;
  if (n >= NN) return;
  int b = off[n], e = off[n + 1];
  float a0 = 0.f, a1 = 0.f, a2 = 0.f;
  for (int i = b; i < e; i++) {
    int s = csr[i];
    a0 += pos[s * 3 + 0];
    a1 += pos[s * 3 + 1];
    a2 += pos[s * 3 + 2];
  }
  float rd = 1.0f / fmaxf((float)(e - b), 1.0f);
  agg3[n * 3 + 0] = a0 * rd;
  agg3[n * 3 + 1] = a1 * rd;
  agg3[n * 3 + 2] = a2 * rd;
}

// ---------------- layer-1 node update (3 -> 128), writes split bf16 ----------
__global__ __launch_bounds__(128) void k_node1(
    const float* __restrict__ agg3, const float* __restrict__ pos,
    const float* __restrict__ wl, const float* __restrict__ bl,
    const float* __restrict__ wr, const float* __restrict__ g,
    const float* __restrict__ be, const float* __restrict__ bm,
    const float* __restrict__ bv, u16* __restrict__ xh, u16* __restrict__ xl) {
  int n = blockIdx.x;
  int c = threadIdx.x;
  __shared__ float sa[3], sp[3];
  if (c < 3) {
    sa[c] = agg3[n * 3 + c];
    sp[c] = pos[n * 3 + c];
  }
  __syncthreads();
  float acc = bl[c];
#pragma unroll
  for (int k = 0; k < 3; k++) {
    acc += sa[k] * wl[k * CC + c];
    acc += sp[k] * wr[k * CC + c];
  }
  float sc = g[c] * rsqrtf(bv[c] + 1e-5f);
  float yv = fmaxf((acc - bm[c]) * sc + be[c], 0.0f);
  u16 h, l;
  split2(yv, h, l);
  xh[(size_t)n * CC + c] = h;
  xl[(size_t)n * CC + c] = l;
}

// ---------------- aggregate (C=128): 16 lanes/node, 8 ch/lane ----------------
__global__ __launch_bounds__(256) void k_aggregate(
    const int* __restrict__ off, const int* __restrict__ csr,
    const u16* __restrict__ xh, const u16* __restrict__ xl,
    u16* __restrict__ aggh, u16* __restrict__ aggl) {
  const int n = blockIdx.x * 16 + (threadIdx.x >> 4);
  const int c0 = (threadIdx.x & 15) * 8;
  const int b = off[n], e = off[n + 1];
  float a[8];
#pragma unroll
  for (int i = 0; i < 8; i++) a[i] = 0.f;
  for (int i = b; i < e; i++) {
    const int s = csr[i];
    uint4 hv = *(const uint4*)(xh + (size_t)s * CC + c0);
    uint4 lv = *(const uint4*)(xl + (size_t)s * CC + c0);
    a[0] += __uint_as_float(hv.x << 16) + __uint_as_float(lv.x << 16);
    a[1] += __uint_as_float(hv.x & 0xffff0000u) + __uint_as_float(lv.x & 0xffff0000u);
    a[2] += __uint_as_float(hv.y << 16) + __uint_as_float(lv.y << 16);
    a[3] += __uint_as_float(hv.y & 0xffff0000u) + __uint_as_float(lv.y & 0xffff0000u);
    a[4] += __uint_as_float(hv.z << 16) + __uint_as_float(lv.z << 16);
    a[5] += __uint_as_float(hv.z & 0xffff0000u) + __uint_as_float(lv.z & 0xffff0000u);
    a[6] += __uint_as_float(hv.w << 16) + __uint_as_float(lv.w << 16);
    a[7] += __uint_as_float(hv.w & 0xffff0000u) + __uint_as_float(lv.w & 0xffff0000u);
  }
  const float rd = 1.0f / fmaxf((float)(e - b), 1.0f);
  u16 hs[8], ls[8];
#pragma unroll
  for (int i = 0; i < 8; i++) {
    float v = a[i] * rd;
    split2(v, hs[i], ls[i]);
  }
  uint4 ho, lo;
  ho.x = (unsigned)hs[0] | ((unsigned)hs[1] << 16);
  ho.y = (unsigned)hs[2] | ((unsigned)hs[3] << 16);
  ho.z = (unsigned)hs[4] | ((unsigned)hs[5] << 16);
  ho.w = (unsigned)hs[6] | ((unsigned)hs[7] << 16);
  lo.x = (unsigned)ls[0] | ((unsigned)ls[1] << 16);
  lo.y = (unsigned)ls[2] | ((unsigned)ls[3] << 16);
  lo.z = (unsigned)ls[4] | ((unsigned)ls[5] << 16);
  lo.w = (unsigned)ls[6] | ((unsigned)ls[7] << 16);
  *(uint4*)(aggh + (size_t)n * CC + c0) = ho;
  *(uint4*)(aggl + (size_t)n * CC + c0) = lo;
}

// ---------------- SAGE MFMA: D = agg@wl + x@wr, BN+ReLU, in-place split x ----
__global__ __launch_bounds__(256) void k_sage_mfma(
    const u16* __restrict__ xh, const u16* __restrict__ xl,
    const u16* __restrict__ ah, const u16* __restrict__ al,
    const u16* __restrict__ wlh, const u16* __restrict__ wll,
    const u16* __restrict__ wrh, const u16* __restrict__ wrl,
    const float* __restrict__ bl, const float* __restrict__ g,
    const float* __restrict__ be, const float* __restrict__ bm,
    const float* __restrict__ bv, u16* __restrict__ yh, u16* __restrict__ yl) {
  const int lane = threadIdx.x & 63;
  const int wave = threadIdx.x >> 6;
  const int c16 = lane & 15;
  const int quad = lane >> 4;
  const int n0 = blockIdx.x * 64 + wave * 16;
  const int rowX = n0 + c16;
  const int rowA = min(rowX, NN - 1);  // agg lives in d_out (not padded): clamp
  const u16* pxh = xh + (size_t)rowX * CC + quad * 8;
  const u16* pxl = xl + (size_t)rowX * CC + quad * 8;
  const u16* pah = ah + (size_t)rowA * CC + quad * 8;
  const u16* pal = al + (size_t)rowA * CC + quad * 8;
  f32x4 acc[8];
#pragma unroll
  for (int t = 0; t < 8; t++) acc[t] = {0.f, 0.f, 0.f, 0.f};
#pragma unroll
  for (int ks = 0; ks < 4; ks++) {
    const int k0 = ks * 32;
    bf16x8 Axh = *(const bf16x8*)(pxh + k0);
    bf16x8 Axl = *(const bf16x8*)(pxl + k0);
    bf16x8 Aah = *(const bf16x8*)(pah + k0);
    bf16x8 Aal = *(const bf16x8*)(pal + k0);
    const size_t wb = (size_t)c16 * CC + k0 + quad * 8;
#pragma unroll
    for (int nt = 0; nt < 8; nt++) {
      const size_t wo = wb + (size_t)nt * (16 * CC);
      bf16x8 Blh = *(const bf16x8*)(wlh + wo);
      bf16x8 Bll = *(const bf16x8*)(wll + wo);
      bf16x8 Brh = *(const bf16x8*)(wrh + wo);
      bf16x8 Brl = *(const bf16x8*)(wrl + wo);
      acc[nt] = MFMA(Aah, Blh, acc[nt]);
      acc[nt] = MFMA(Axh, Brh, acc[nt]);
      acc[nt] = MFMA(Aal, Blh, acc[nt]);
      acc[nt] = MFMA(Axl, Brh, acc[nt]);
      acc[nt] = MFMA(Aah, Bll, acc[nt]);
      acc[nt] = MFMA(Axh, Brl, acc[nt]);
    }
  }
#pragma unroll
  for (int nt = 0; nt < 8; nt++) {
    const int col = nt * 16 + c16;
    const float blc = bl[col];
    const float sc = g[col] * rsqrtf(bv[col] + 1e-5f);
    const float mm = bm[col];
    const float bb = be[col];
#pragma unroll
    for (int r = 0; r < 4; r++) {
      const int node = n0 + quad * 4 + r;
      if (node < NN) {
        float yv = fmaxf((acc[nt][r] + blc - mm) * sc + bb, 0.0f);
        u16 h, l;
        split2(yv, h, l);
        yh[(size_t)node * CC + col] = h;
        yl[(size_t)node * CC + col] = l;
      }
    }
  }
}

// ---------------- dense MFMA: MODE 0 = relu+split, 1 = split, 2 = fp32 out ----
template <int MODE>
__global__ __launch_bounds__(256) void k_dense_mfma(
    const u16* __restrict__ xh, const u16* __restrict__ xl,
    const u16* __restrict__ wh, const u16* __restrict__ wl_,
    const float* __restrict__ bias, u16* __restrict__ yh,
    u16* __restrict__ yl, float* __restrict__ yf) {
  const int lane = threadIdx.x & 63;
  const int wave = threadIdx.x >> 6;
  const int c16 = lane & 15;
  const int quad = lane >> 4;
  const int n0 = blockIdx.x * 64 + wave * 16;
  const int rowX = n0 + c16;
  const u16* pxh = xh + (size_t)rowX * CC + quad * 8;
  const u16* pxl = xl + (size_t)rowX * CC + quad * 8;
  f32x4 acc[8];
#pragma unroll
  for (int t = 0; t < 8; t++) acc[t] = {0.f, 0.f, 0.f, 0.f};
#pragma unroll
  for (int ks = 0; ks < 4; ks++) {
    const int k0 = ks * 32;
    bf16x8 Axh = *(const bf16x8*)(pxh + k0);
    bf16x8 Axl = *(const bf16x8*)(pxl + k0);
    const size_t wb = (size_t)c16 * CC + k0 + quad * 8;
#pragma unroll
    for (int nt = 0; nt < 8; nt++) {
      const size_t wo = wb + (size_t)nt * (16 * CC);
      bf16x8 Bh = *(const bf16x8*)(wh + wo);
      bf16x8 Bl = *(const bf16x8*)(wl_ + wo);
      acc[nt] = MFMA(Axh, Bh, acc[nt]);
      acc[nt] = MFMA(Axl, Bh, acc[nt]);
      acc[nt] = MFMA(Axh, Bl, acc[nt]);
    }
  }
#pragma unroll
  for (int nt = 0; nt < 8; nt++) {
    const int col = nt * 16 + c16;
    const float bc = bias[col];
#pragma unroll
    for (int r = 0; r < 4; r++) {
      const int node = n0 + quad * 4 + r;
      if (node < NN) {
        float yv = acc[nt][r] + bc;
        if (MODE == 0) yv = fmaxf(yv, 0.0f);
        if (MODE == 2) {
          yf[(size_t)node * CC + col] = yv;
        } else {
          u16 h, l;
          split2(yv, h, l);
          yh[(size_t)node * CC + col] = h;
          yl[(size_t)node * CC + col] = l;
        }
      }
    }
  }
}

extern "C" void kernel_launch(void* const* d_in, const int* in_sizes, int n_in,
                              void* d_out, int out_size, void* d_ws,
                              size_t ws_size, hipStream_t stream) {
  const float* pos = (const float*)d_in[0];
  const int* ei = (const int*)d_in[1];
  const int* src = ei;
  const int* dst = ei + EE;
  auto P = [&](int i) { return (const float*)d_in[i]; };

  // ws: degi[N] | cursor[N] | off[N+8] | csr[E] | wph | wpl | xh | xl  (~59.4 MB)
  int* degi = (int*)d_ws;
  int* cursor = degi + NN;
  int* off = cursor + NN;
  int* csr = off + NN + 8;
  u16* wph = (u16*)(csr + EE);
  u16* wpl = wph + 9 * 16384;
  u16* xh = wpl + 9 * 16384;
  u16* xl = xh + (size_t)NP * CC;

  // agg scratch lives in d_out until the final dense overwrites it
  u16* aggh = (u16*)d_out;
  u16* aggl = aggh + (size_t)NN * CC;

  hipMemsetAsync(degi, 0, NN * sizeof(int), stream);
  hipMemsetAsync(cursor, 0, NN * sizeof(int), stream);

  k_count<<<(EE + 255) / 256, 256, 0, stream>>>(dst, degi);
  k_scan<<<1, 1024, 0, stream>>>(degi, off);
  k_fill<<<(EE + 255) / 256, 256, 0, stream>>>(src, dst, off, cursor, csr);

  WPtrs wp;
  const int wsrc[9] = {9, 11, 16, 18, 23, 25, 30, 32, 34};
  for (int i = 0; i < 9; i++) wp.w[i] = P(wsrc[i]);
  k_packw<<<(9 * 16384) / 256, 256, 0, stream>>>(wp, wph, wpl);

  // layer 1 (Cin=3): agg3 in d_out scratch (1.2 MB)
  k_agg3<<<(NN + 255) / 256, 256, 0, stream>>>(off, csr, pos, (float*)d_out);
  k_node1<<<NN, 128, 0, stream>>>((const float*)d_out, pos, P(2), P(3), P(4),
                                  P(5), P(6), P(7), P(8), xh, xl);

  // layers 2..4
  const int NB = NP / 64;  // 1563
  for (int l = 1; l < 4; l++) {
    int base = 2 + 7 * l;
    int mat = (l - 1) * 2;
    k_aggregate<<<NN / 16, 256, 0, stream>>>(off, csr, xh, xl, aggh, aggl);
    k_sage_mfma<<<NB, 256, 0, stream>>>(
        xh, xl, aggh, aggl, wph + (size_t)mat * 16384, wpl + (size_t)mat * 16384,
        wph + (size_t)(mat + 1) * 16384, wpl + (size_t)(mat + 1) * 16384,
        P(base + 1), P(base + 3), P(base + 4), P(base + 5), P(base + 6), xh, xl);
  }

  // FC head
  k_dense_mfma<0><<<NB, 256, 0, stream>>>(xh, xl, wph + 6 * 16384,
                                          wpl + 6 * 16384, P(31), xh, xl, nullptr);
  k_dense_mfma<1><<<NB, 256, 0, stream>>>(xh, xl, wph + 7 * 16384,
                                          wpl + 7 * 16384, P(33), xh, xl, nullptr);
  k_dense_mfma<2><<<NB, 256, 0, stream>>>(xh, xl, wph + 8 * 16384,
                                          wpl + 8 * 16384, P(35), nullptr, nullptr,
                                          (float*)d_out);
}

// Round 5
// 761.687 us; speedup vs baseline: 12.2187x; 2.1279x over previous
//
#include <hip/hip_runtime.h>

#define NN 100000
#define EE 1600000
#define CC 128
#define NP 100032  // padded to 64-row tiles (1563 * 64)

typedef _Float16 f16;
typedef __attribute__((ext_vector_type(8))) f16 f16x8;
typedef __attribute__((ext_vector_type(4))) float f32x4;

#define MFMA16(a, b, c) __builtin_amdgcn_mfma_f32_16x16x32_f16(a, b, c, 0, 0, 0)

// ---------------- CSR build ----------------
__global__ __launch_bounds__(256) void k_count(const int* __restrict__ dst,
                                               int* __restrict__ degi) {
  int e = blockIdx.x * 256 + threadIdx.x;
  if (e < EE) atomicAdd(&degi[dst[e]], 1);
}

// phase 1: per-block (1024 elems) sums
__global__ __launch_bounds__(1024) void k_scan1(const int* __restrict__ degi,
                                                int* __restrict__ bsum) {
  __shared__ int sh[1024];
  int t = threadIdx.x;
  int i = blockIdx.x * 1024 + t;
  sh[t] = (i < NN) ? degi[i] : 0;
  __syncthreads();
  for (int d = 512; d > 0; d >>= 1) {
    if (t < d) sh[t] += sh[t + d];
    __syncthreads();
  }
  if (t == 0) bsum[blockIdx.x] = sh[0];
}

// phase 2: scan the 98 block sums (single block)
__global__ __launch_bounds__(128) void k_scan2(const int* __restrict__ bsum,
                                               int* __restrict__ bbase,
                                               int* __restrict__ off) {
  __shared__ int sh[128];
  int t = threadIdx.x;
  int v = (t < 98) ? bsum[t] : 0;
  sh[t] = v;
  __syncthreads();
  for (int d = 1; d < 128; d <<= 1) {
    int a = (t >= d) ? sh[t - d] : 0;
    __syncthreads();
    sh[t] += a;
    __syncthreads();
  }
  if (t < 98) bbase[t] = sh[t] - v;  // exclusive
  if (t == 127) off[NN] = sh[127];   // total == EE
}

// phase 3: block-local exclusive scan + base
__global__ __launch_bounds__(1024) void k_scan3(const int* __restrict__ degi,
                                                const int* __restrict__ bbase,
                                                int* __restrict__ off) {
  __shared__ int sh[1024];
  int t = threadIdx.x;
  int i = blockIdx.x * 1024 + t;
  int v = (i < NN) ? degi[i] : 0;
  sh[t] = v;
  __syncthreads();
  for (int d = 1; d < 1024; d <<= 1) {
    int a = (t >= d) ? sh[t - d] : 0;
    __syncthreads();
    sh[t] += a;
    __syncthreads();
  }
  if (i < NN) off[i] = bbase[blockIdx.x] + sh[t] - v;
}

__global__ __launch_bounds__(256) void k_fill(const int* __restrict__ src,
                                              const int* __restrict__ dst,
                                              const int* __restrict__ off,
                                              int* __restrict__ cursor,
                                              int* __restrict__ csr) {
  int e = blockIdx.x * 256 + threadIdx.x;
  if (e < EE) {
    int d = dst[e];
    int p = atomicAdd(&cursor[d], 1);
    csr[off[d] + p] = src[e];
  }
}

// ------- weight pack: fp32 [k][n] -> fp16 in MFMA B-fragment order ----------
// packed idx = ((nt*4 + ks)*64 + lane)*8 + j ; k=ks*32+quad*8+j, n=nt*16+c16
struct WPtrs { const float* w[9]; };
__global__ __launch_bounds__(256) void k_packw(WPtrs wp, f16* __restrict__ out) {
  int t = blockIdx.x * 256 + threadIdx.x;  // 9 * 16384
  int mat = t >> 14;
  int idx = t & 16383;
  int j = idx & 7;
  int lane = (idx >> 3) & 63;
  int ks = (idx >> 9) & 3;
  int nt = idx >> 11;
  int c16 = lane & 15, quad = lane >> 4;
  int k = ks * 32 + quad * 8 + j;
  int n = nt * 16 + c16;
  out[(size_t)mat * 16384 + idx] = (f16)wp.w[mat][k * CC + n];
}

// ---------------- layer-1 aggregate (Cin=3) ----------------
__global__ __launch_bounds__(256) void k_agg3(const int* __restrict__ off,
                                              const int* __restrict__ csr,
                                              const float* __restrict__ pos,
                                              float* __restrict__ agg3) {
  int n = blockIdx.x * 256 + threadIdx.x;
  if (n >= NN) return;
  int b = off[n], e = off[n + 1];
  float a0 = 0.f, a1 = 0.f, a2 = 0.f;
  for (int i = b; i < e; i++) {
    int s = csr[i];
    a0 += pos[s * 3 + 0];
    a1 += pos[s * 3 + 1];
    a2 += pos[s * 3 + 2];
  }
  float rd = 1.0f / fmaxf((float)(e - b), 1.0f);
  agg3[n * 3 + 0] = a0 * rd;
  agg3[n * 3 + 1] = a1 * rd;
  agg3[n * 3 + 2] = a2 * rd;
}

// ---------------- layer-1 node update (3 -> 128), writes fp16 ----------
__global__ __launch_bounds__(128) void k_node1(
    const float* __restrict__ agg3, const float* __restrict__ pos,
    const float* __restrict__ wl, const float* __restrict__ bl,
    const float* __restrict__ wr, const float* __restrict__ g,
    const float* __restrict__ be, const float* __restrict__ bm,
    const float* __restrict__ bv, f16* __restrict__ x) {
  int n = blockIdx.x;
  int c = threadIdx.x;
  __shared__ float sa[3], sp[3];
  if (c < 3) {
    sa[c] = agg3[n * 3 + c];
    sp[c] = pos[n * 3 + c];
  }
  __syncthreads();
  float acc = bl[c];
#pragma unroll
  for (int k = 0; k < 3; k++) {
    acc += sa[k] * wl[k * CC + c];
    acc += sp[k] * wr[k * CC + c];
  }
  float sc = g[c] * rsqrtf(bv[c] + 1e-5f);
  float yv = fmaxf((acc - bm[c]) * sc + be[c], 0.0f);
  x[(size_t)n * CC + c] = (f16)yv;
}

// ---------------- aggregate (C=128): 16 lanes/node, 8 fp16 ch/lane ----------
__global__ __launch_bounds__(256) void k_aggregate(const int* __restrict__ off,
                                                   const int* __restrict__ csr,
                                                   const f16* __restrict__ x,
                                                   f16* __restrict__ agg) {
  const int n = blockIdx.x * 16 + (threadIdx.x >> 4);
  const int c0 = (threadIdx.x & 15) * 8;
  const int b = off[n], e = off[n + 1];
  float a[8];
#pragma unroll
  for (int i = 0; i < 8; i++) a[i] = 0.f;
  for (int i = b; i < e; i++) {
    const int s = csr[i];
    f16x8 v = *(const f16x8*)(x + (size_t)s * CC + c0);
#pragma unroll
    for (int q = 0; q < 8; q++) a[q] += (float)v[q];
  }
  const float rd = 1.0f / fmaxf((float)(e - b), 1.0f);
  f16x8 o;
#pragma unroll
  for (int q = 0; q < 8; q++) o[q] = (f16)(a[q] * rd);
  *(f16x8*)(agg + (size_t)n * CC + c0) = o;
}

// ---------------- SAGE MFMA fp16: D = agg@wl + x@wr, BN+ReLU, in-place ------
__global__ __launch_bounds__(256) void k_sage_mfma(
    f16* __restrict__ x, const f16* __restrict__ agg,
    const f16* __restrict__ wl, const f16* __restrict__ wr,
    const float* __restrict__ bl, const float* __restrict__ g,
    const float* __restrict__ be, const float* __restrict__ bm,
    const float* __restrict__ bv) {
  const int lane = threadIdx.x & 63;
  const int wave = threadIdx.x >> 6;
  const int c16 = lane & 15;
  const int quad = lane >> 4;
  const int n0 = blockIdx.x * 64 + wave * 16;
  const int rowX = n0 + c16;
  const int rowA = min(rowX, NN - 1);  // agg (in d_out) is not padded
  const f16* px = x + (size_t)rowX * CC + quad * 8;
  const f16* pa = agg + (size_t)rowA * CC + quad * 8;
  f32x4 acc[8];
#pragma unroll
  for (int t = 0; t < 8; t++) acc[t] = {0.f, 0.f, 0.f, 0.f};
#pragma unroll
  for (int ks = 0; ks < 4; ks++) {
    f16x8 Ax = *(const f16x8*)(px + ks * 32);
    f16x8 Aa = *(const f16x8*)(pa + ks * 32);
#pragma unroll
    for (int nt = 0; nt < 8; nt++) {
      const size_t wo = (size_t)((nt * 4 + ks) * 64 + lane) * 8;
      f16x8 Bl = *(const f16x8*)(wl + wo);
      f16x8 Br = *(const f16x8*)(wr + wo);
      acc[nt] = MFMA16(Aa, Bl, acc[nt]);
      acc[nt] = MFMA16(Ax, Br, acc[nt]);
    }
  }
#pragma unroll
  for (int nt = 0; nt < 8; nt++) {
    const int col = nt * 16 + c16;
    const float blc = bl[col];
    const float sc = g[col] * rsqrtf(bv[col] + 1e-5f);
    const float mm = bm[col];
    const float bb = be[col];
#pragma unroll
    for (int r = 0; r < 4; r++) {
      const int node = n0 + quad * 4 + r;
      if (node < NN) {
        float yv = fmaxf((acc[nt][r] + blc - mm) * sc + bb, 0.0f);
        x[(size_t)node * CC + col] = (f16)yv;
      }
    }
  }
}

// ---------------- dense MFMA fp16: MODE 0 relu->x, 1 ->x, 2 fp32 ->out ------
template <int MODE>
__global__ __launch_bounds__(256) void k_dense_mfma(f16* __restrict__ x,
                                                    const f16* __restrict__ w,
                                                    const float* __restrict__ bias,
                                                    float* __restrict__ yf) {
  const int lane = threadIdx.x & 63;
  const int wave = threadIdx.x >> 6;
  const int c16 = lane & 15;
  const int quad = lane >> 4;
  const int n0 = blockIdx.x * 64 + wave * 16;
  const int rowX = n0 + c16;
  const f16* px = x + (size_t)rowX * CC + quad * 8;
  f32x4 acc[8];
#pragma unroll
  for (int t = 0; t < 8; t++) acc[t] = {0.f, 0.f, 0.f, 0.f};
#pragma unroll
  for (int ks = 0; ks < 4; ks++) {
    f16x8 Ax = *(const f16x8*)(px + ks * 32);
#pragma unroll
    for (int nt = 0; nt < 8; nt++) {
      f16x8 B = *(const f16x8*)(w + (size_t)((nt * 4 + ks) * 64 + lane) * 8);
      acc[nt] = MFMA16(Ax, B, acc[nt]);
    }
  }
#pragma unroll
  for (int nt = 0; nt < 8; nt++) {
    const int col = nt * 16 + c16;
    const float bc = bias[col];
#pragma unroll
    for (int r = 0; r < 4; r++) {
      const int node = n0 + quad * 4 + r;
      if (node < NN) {
        float yv = acc[nt][r] + bc;
        if (MODE == 0) yv = fmaxf(yv, 0.0f);
        if (MODE == 2)
          yf[(size_t)node * CC + col] = yv;
        else
          x[(size_t)node * CC + col] = (f16)yv;
      }
    }
  }
}

extern "C" void kernel_launch(void* const* d_in, const int* in_sizes, int n_in,
                              void* d_out, int out_size, void* d_ws,
                              size_t ws_size, hipStream_t stream) {
  const float* pos = (const float*)d_in[0];
  const int* ei = (const int*)d_in[1];
  const int* src = ei;
  const int* dst = ei + EE;
  auto P = [&](int i) { return (const float*)d_in[i]; };

  // ws: degi[N] | cursor[N] | off[N+2] | bsum[128] | bbase[128] | csr[E] |
  //     wp16[9*16384] f16 | x[NP*CC] f16   (~33 MB)
  int* degi = (int*)d_ws;
  int* cursor = degi + NN;
  int* off = cursor + NN;
  int* bsum = off + NN + 2;
  int* bbase = bsum + 128;
  int* csr = bbase + 128;
  f16* wp16 = (f16*)(csr + EE);
  f16* x = wp16 + 9 * 16384;

  f16* agg = (f16*)d_out;  // scratch until the final dense overwrites d_out

  hipMemsetAsync(degi, 0, NN * sizeof(int), stream);
  hipMemsetAsync(cursor, 0, NN * sizeof(int), stream);

  k_count<<<(EE + 255) / 256, 256, 0, stream>>>(dst, degi);
  const int SB = (NN + 1023) / 1024;  // 98
  k_scan1<<<SB, 1024, 0, stream>>>(degi, bsum);
  k_scan2<<<1, 128, 0, stream>>>(bsum, bbase, off);
  k_scan3<<<SB, 1024, 0, stream>>>(degi, bbase, off);
  k_fill<<<(EE + 255) / 256, 256, 0, stream>>>(src, dst, off, cursor, csr);

  WPtrs wp;
  const int wsrc[9] = {9, 11, 16, 18, 23, 25, 30, 32, 34};
  for (int i = 0; i < 9; i++) wp.w[i] = P(wsrc[i]);
  k_packw<<<(9 * 16384) / 256, 256, 0, stream>>>(wp, wp16);

  // layer 1 (Cin=3): agg3 fp32 in d_out scratch (1.2 MB)
  k_agg3<<<(NN + 255) / 256, 256, 0, stream>>>(off, csr, pos, (float*)d_out);
  k_node1<<<NN, 128, 0, stream>>>((const float*)d_out, pos, P(2), P(3), P(4),
                                  P(5), P(6), P(7), P(8), x);

  // layers 2..4
  const int NB = NP / 64;  // 1563
  for (int l = 1; l < 4; l++) {
    int base = 2 + 7 * l;
    int mat = (l - 1) * 2;
    k_aggregate<<<NN / 16, 256, 0, stream>>>(off, csr, x, agg);
    k_sage_mfma<<<NB, 256, 0, stream>>>(
        x, agg, wp16 + (size_t)mat * 16384, wp16 + (size_t)(mat + 1) * 16384,
        P(base + 1), P(base + 3), P(base + 4), P(base + 5), P(base + 6));
  }

  // FC head
  k_dense_mfma<0><<<NB, 256, 0, stream>>>(x, wp16 + (size_t)6 * 16384, P(31), nullptr);
  k_dense_mfma<1><<<NB, 256, 0, stream>>>(x, wp16 + (size_t)7 * 16384, P(33), nullptr);
  k_dense_mfma<2><<<NB, 256, 0, stream>>>(x, wp16 + (size_t)8 * 16384, P(35),
                                          (float*)d_out);
}